// Round 1
// baseline (64.371 us; speedup 1.0000x reference)
//
#include <hip/hip_runtime.h>

// Kernel 1: compute per-row position-within-segment into pos[] (int32).
// One block, 512 threads; Hillis-Steele inclusive scan of dia_len in LDS,
// then each thread writes pos[start..start+len) = 0..len-1.
__global__ void pe_pos_kernel(const int* __restrict__ dia_len, int n_seg,
                              int* __restrict__ pos, int n_rows) {
    __shared__ int s[512];
    const int t = threadIdx.x;
    int len = (t < n_seg) ? dia_len[t] : 0;
    s[t] = len;
    __syncthreads();
    #pragma unroll
    for (int off = 1; off < 512; off <<= 1) {
        int v = (t >= off) ? s[t - off] : 0;
        __syncthreads();
        s[t] += v;
        __syncthreads();
    }
    const int start = s[t] - len;   // exclusive prefix = segment start row
    for (int i = 0; i < len; ++i) {
        const int r = start + i;
        if (r < n_rows) pos[r] = i;
    }
}

// Kernel 2: out = x + pe[pos[row]], vectorized float4, grid-stride.
// D_MODEL = 1024 floats = 256 float4 per row.
__global__ void pe_add_kernel(const float4* __restrict__ x,
                              const float4* __restrict__ pe,
                              const int* __restrict__ pos,
                              float4* __restrict__ out, long n4) {
    long i = (long)blockIdx.x * blockDim.x + threadIdx.x;
    const long stride = (long)gridDim.x * blockDim.x;
    for (; i < n4; i += stride) {
        const int row = (int)(i >> 8);      // / 256 float4 per row
        const int c   = (int)(i & 255);     // col in float4 units
        const int p   = pos[row];
        const float4 xv = x[i];
        const float4 pv = pe[(long)p * 256 + c];
        float4 o;
        o.x = xv.x + pv.x;
        o.y = xv.y + pv.y;
        o.z = xv.z + pv.z;
        o.w = xv.w + pv.w;
        out[i] = o;
    }
}

extern "C" void kernel_launch(void* const* d_in, const int* in_sizes, int n_in,
                              void* d_out, int out_size, void* d_ws, size_t ws_size,
                              hipStream_t stream) {
    const float* x  = (const float*)d_in[0];
    const float* pe = (const float*)d_in[1];
    const int*   dl = (const int*)d_in[2];
    float*       out = (float*)d_out;

    const int n_seg  = in_sizes[2];          // 512
    const int n_rows = out_size / 1024;      // 32768 (D_MODEL = 1024)
    int* pos = (int*)d_ws;                   // n_rows * 4 B = 128 KB scratch

    pe_pos_kernel<<<1, 512, 0, stream>>>(dl, n_seg, pos, n_rows);

    const long n4 = (long)out_size / 4;      // float4 element count
    pe_add_kernel<<<2048, 256, 0, stream>>>(
        (const float4*)x, (const float4*)pe, pos, (float4*)out, n4);
}

// Round 2
// 50.436 us; speedup vs baseline: 1.2763x; 1.2763x over previous
//
#include <hip/hip_runtime.h>

// Fused: out[row][c] = x[row][c] + pe[pos(row)][c], pos(row) = row - seg_start(row).
// Each block scans dia_len (n_seg <= 512) in LDS, then grid-strides over float4s.
// D_MODEL = 1024 floats = 256 float4 per row, so row = i >> 8 is wave-uniform.
__global__ void __launch_bounds__(512)
pe_fused_kernel(const float4* __restrict__ x,
                const float4* __restrict__ pe,
                const int* __restrict__ dia_len, int n_seg,
                float4* __restrict__ out, long n4) {
    __shared__ int cum[512];                 // inclusive cumsum of dia_len
    const int t = threadIdx.x;
    int v = (t < n_seg) ? dia_len[t] : 0;
    cum[t] = v;
    __syncthreads();
    #pragma unroll
    for (int off = 1; off < 512; off <<= 1) {
        int add = (t >= off) ? cum[t - off] : 0;
        __syncthreads();
        cum[t] += add;
        __syncthreads();
    }

    long i = (long)blockIdx.x * blockDim.x + threadIdx.x;
    const long stride = (long)gridDim.x * blockDim.x;
    for (; i < n4; i += stride) {
        const int row = (int)(i >> 8);       // float4-row (wave-uniform)
        // first segment s in [0, n_seg) with cum[s] > row  (9 LDS broadcast reads)
        int lo = 0, hi = n_seg;
        while (lo < hi) {
            const int mid = (lo + hi) >> 1;
            if (cum[mid] > row) hi = mid; else lo = mid + 1;
        }
        const int start = (lo > 0) ? cum[lo - 1] : 0;
        const int p = row - start;           // position within segment
        const float4 xv = x[i];
        const float4 pv = pe[((long)p << 8) | (i & 255)];
        float4 o;
        o.x = xv.x + pv.x;
        o.y = xv.y + pv.y;
        o.z = xv.z + pv.z;
        o.w = xv.w + pv.w;
        out[i] = o;
    }
}

extern "C" void kernel_launch(void* const* d_in, const int* in_sizes, int n_in,
                              void* d_out, int out_size, void* d_ws, size_t ws_size,
                              hipStream_t stream) {
    const float* x  = (const float*)d_in[0];
    const float* pe = (const float*)d_in[1];
    const int*   dl = (const int*)d_in[2];
    float*       out = (float*)d_out;

    const int n_seg = in_sizes[2];           // 512 (must be <= 512 for LDS scan)
    const long n4 = (long)out_size / 4;      // float4 element count

    // 1024 blocks x 512 threads = 524288 threads -> 16 grid-stride iterations;
    // ~4 blocks/CU resident (32-wave cap), scan amortized over all iterations.
    pe_fused_kernel<<<1024, 512, 0, stream>>>(
        (const float4*)x, (const float4*)pe, dl, n_seg, (float4*)out, n4);
}